// Round 8
// baseline (560.108 us; speedup 1.0000x reference)
//
#include <hip/hip_runtime.h>
#include <hip/hip_cooperative_groups.h>
#include <cstdint>
#include <cstddef>

namespace cg = cooperative_groups;

// ---------- types ----------
typedef __attribute__((ext_vector_type(8))) __bf16 bf16x8;   // MFMA A/B frag (4 VGPRs)
typedef __attribute__((ext_vector_type(4))) float  f32x4;    // MFMA C/D frag

__device__ __forceinline__ unsigned short f32_to_bf16(float f) {
    union { float f; unsigned int u; } cv;
    cv.f = f;
    unsigned int u = cv.u;
    return (unsigned short)((u + 0x7fffu + ((u >> 16) & 1u)) >> 16);  // RNE
}

__device__ __forceinline__ float bf16_to_f32(unsigned short h) {
    union { unsigned int u; float f; } cv;
    cv.u = ((unsigned int)h) << 16;
    return cv.f;
}

// async global->LDS, 16 bytes per lane. LDS dest is wave-uniform base + lane*16.
__device__ __forceinline__ void async_copy16(const unsigned short* g, unsigned short* lds) {
    __builtin_amdgcn_global_load_lds(
        (const __attribute__((address_space(1))) unsigned int*)g,
        (__attribute__((address_space(3))) unsigned int*)lds,
        16, 0, 0);
}

// ---------- prefetch double-buffered GEMM core, BK=32 (R4 proven) ----------
__device__ __forceinline__ void gemm_core_pf(
    const unsigned short* __restrict__ A, const unsigned short* __restrict__ B,
    int K, int rowBase, int colBase, int kBeg, int kEnd,
    unsigned short* ldsA, unsigned short* ldsB, f32x4 acc[4][4])
{
    const int tid  = threadIdx.x;
    const int lane = tid & 63;
    const int wave = tid >> 6;
    const int quad = lane >> 4;
    const int r    = lane & 15;
    const int wm   = wave >> 1;
    const int wn   = wave & 1;

    const int c1 = tid + 256;
    const long aOff0 = (long)(rowBase + (tid >> 2)) * K + (tid & 3) * 8;
    const long aOff1 = (long)(rowBase + (c1  >> 2)) * K + (c1  & 3) * 8;
    const long bOff0 = (long)(colBase + (tid >> 2)) * K + (tid & 3) * 8;
    const long bOff1 = (long)(colBase + (c1  >> 2)) * K + (c1  & 3) * 8;
    unsigned short* ldsA0 = ldsA + tid * 8;
    unsigned short* ldsA1 = ldsA + c1 * 8;
    unsigned short* ldsB0 = ldsB + tid * 8;
    unsigned short* ldsB1 = ldsB + c1 * 8;

    const int aReadOff = (wm * 64 + r) * 32 + quad * 8;
    const int bReadOff = (wn * 64 + r) * 32 + quad * 8;

    const int nSteps = (kEnd - kBeg) >> 5;

    async_copy16(A + aOff0 + kBeg, ldsA0);
    async_copy16(A + aOff1 + kBeg, ldsA1);
    async_copy16(B + bOff0 + kBeg, ldsB0);
    async_copy16(B + bOff1 + kBeg, ldsB1);

    for (int s = 0; s < nSteps; ++s) {
        const int cur = (s & 1) << 12;
        const int nxt = cur ^ 4096;
        __builtin_amdgcn_s_waitcnt(0);          // tile s arrived
        __syncthreads();                        // visible; buf[nxt] free
        if (s + 1 < nSteps) {
            const int kn = kBeg + ((s + 1) << 5);
            async_copy16(A + aOff0 + kn, ldsA0 + nxt);
            async_copy16(A + aOff1 + kn, ldsA1 + nxt);
            async_copy16(B + bOff0 + kn, ldsB0 + nxt);
            async_copy16(B + bOff1 + kn, ldsB1 + nxt);
        }
        bf16x8 af[4], bfr[4];
#pragma unroll
        for (int i = 0; i < 4; ++i)
            af[i] = *(const bf16x8*)(ldsA + cur + aReadOff + i * 16 * 32);
#pragma unroll
        for (int j = 0; j < 4; ++j)
            bfr[j] = *(const bf16x8*)(ldsB + cur + bReadOff + j * 16 * 32);
#pragma unroll
        for (int i = 0; i < 4; ++i)
#pragma unroll
            for (int j = 0; j < 4; ++j)
                acc[i][j] = __builtin_amdgcn_mfma_f32_16x16x32_bf16(af[i], bfr[j], acc[i][j], 0, 0, 0);
    }
}

// ================= fused persistent cooperative kernel =================
// Phases separated by grid.sync():
//  0: fp32->bf16 casts (+ lsum zero, + Out zero if atomic fallback)
//  1: proj q/k/vt (768 tiles)
//  2: scores P = exp2(s*qk^T), lsum atomics (1024 tiles)
//  3: out split-K x4 -> bf16 parts (1024 tiles)
//  4: reduce 4 parts + normalize -> Out
__global__ __launch_bounds__(256, 4)
void fused_all(const float* __restrict__ x,  const float* __restrict__ y,
               const float* __restrict__ wq, const float* __restrict__ wk,
               const float* __restrict__ wv,
               const float* __restrict__ bq, const float* __restrict__ bk,
               const float* __restrict__ bv,
               unsigned short* __restrict__ xb,  unsigned short* __restrict__ yb,
               unsigned short* __restrict__ wqb, unsigned short* __restrict__ wkb,
               unsigned short* __restrict__ wvb,
               unsigned short* __restrict__ qb, unsigned short* __restrict__ kb,
               unsigned short* __restrict__ vtb,
               unsigned short* __restrict__ P, unsigned short* __restrict__ parts,
               float* __restrict__ lsum, float* __restrict__ Out, int useParts)
{
    cg::grid_group grid = cg::this_grid();
    __shared__ __align__(16) unsigned short ldsA[2 * 128 * 32];
    __shared__ __align__(16) unsigned short ldsB[2 * 128 * 32];

    const int nb   = gridDim.x;
    const int tid  = threadIdx.x;
    const int lane = tid & 63;
    const int wave = tid >> 6;
    const int quad = lane >> 4;
    const int r    = lane & 15;

    // ---- phase 0: casts ----
    for (int b = blockIdx.x; b < 11264; b += nb) {
        const float* s; unsigned short* d; int base;
        if      (b < 4096)  { s = x;  d = xb;  base = b; }
        else if (b < 8192)  { s = y;  d = yb;  base = b - 4096; }
        else if (b < 9216)  { s = wq; d = wqb; base = b - 8192; }
        else if (b < 10240) { s = wk; d = wkb; base = b - 9216; }
        else                { s = wv; d = wvb; base = b - 10240; }
        int i = base * 256 + tid;
        float4 v = ((const float4*)s)[i];
        ushort4 o;
        o.x = f32_to_bf16(v.x);
        o.y = f32_to_bf16(v.y);
        o.z = f32_to_bf16(v.z);
        o.w = f32_to_bf16(v.w);
        ((ushort4*)d)[i] = o;
    }
    if (blockIdx.x == 0) {
        float4 z = {0.f, 0.f, 0.f, 0.f};
        for (int t = tid; t < 1024; t += 256) ((float4*)lsum)[t] = z;  // lsum[4096]
    }
    if (!useParts) {
        float4 z = {0.f, 0.f, 0.f, 0.f};
        for (int i = blockIdx.x * 256 + tid; i < 1024 * 1024; i += nb * 256)
            ((float4*)Out)[i] = z;
    }
    grid.sync();

    // ---- phase 1: projections (768 tiles) ----
    for (int t = blockIdx.x; t < 768; t += nb) {
        const int z = t >> 8;
        const int rb = t & 255;
        const unsigned short *A, *B;
        unsigned short* C;
        const float* bias;
        int N, rowBase, colBase;
        bool biasPerRow;
        if (z == 0) {
            A = xb; B = wqb; C = qb; bias = bq; N = 1024; biasPerRow = false;
            colBase = (rb >> 5) * 128; rowBase = (rb & 31) * 128;
        } else if (z == 1) {
            A = yb; B = wkb; C = kb; bias = bk; N = 1024; biasPerRow = false;
            colBase = (rb >> 5) * 128; rowBase = (rb & 31) * 128;
        } else {
            A = wvb; B = yb; C = vtb; bias = bv; N = 4096; biasPerRow = true;
            colBase = (rb >> 3) * 128; rowBase = (rb & 7) * 128;
        }

        f32x4 acc[4][4];
#pragma unroll
        for (int i = 0; i < 4; ++i)
#pragma unroll
            for (int j = 0; j < 4; ++j)
                acc[i][j] = (f32x4){0.f, 0.f, 0.f, 0.f};

        gemm_core_pf(A, B, 1024, rowBase, colBase, 0, 1024, ldsA, ldsB, acc);

        const int orow0 = rowBase + (wave >> 1) * 64 + quad * 4;
        const int ocol0 = colBase + (wave & 1) * 64 + r;
#pragma unroll
        for (int i = 0; i < 4; ++i)
#pragma unroll
            for (int e = 0; e < 4; ++e) {
                const int row = orow0 + i * 16 + e;
                const float brow = biasPerRow ? bias[row] : 0.f;
#pragma unroll
                for (int j = 0; j < 4; ++j) {
                    const int col = ocol0 + j * 16;
                    const float bb = biasPerRow ? brow : bias[col];
                    C[(long)row * N + col] = f32_to_bf16(acc[i][j][e] + bb);
                }
            }
    }
    grid.sync();

    // ---- phase 2: scores (1024 tiles) ----
    const float scale2 = 1.4426950408889634f / 32.0f;  // log2(e)/sqrt(H)
    for (int t = blockIdx.x; t < 1024; t += nb) {
        const int rowBase = (t >> 5) * 128;
        const int colBase = (t & 31) * 128;

        f32x4 acc[4][4];
#pragma unroll
        for (int i = 0; i < 4; ++i)
#pragma unroll
            for (int j = 0; j < 4; ++j)
                acc[i][j] = (f32x4){0.f, 0.f, 0.f, 0.f};

        gemm_core_pf(qb, kb, 1024, rowBase, colBase, 0, 1024, ldsA, ldsB, acc);

        const int orow0 = rowBase + (wave >> 1) * 64 + quad * 4;
        const int ocol0 = colBase + (wave & 1) * 64 + r;
#pragma unroll
        for (int i = 0; i < 4; ++i)
#pragma unroll
            for (int e = 0; e < 4; ++e) {
                const int row = orow0 + i * 16 + e;
                float rs = 0.f;
#pragma unroll
                for (int j = 0; j < 4; ++j) {
                    const int col = ocol0 + j * 16;
                    const float p = exp2f(acc[i][j][e] * scale2);
                    rs += p;
                    P[(long)row * 4096 + col] = f32_to_bf16(p);
                }
#pragma unroll
                for (int m = 1; m < 16; m <<= 1) rs += __shfl_xor(rs, m, 64);
                if (r == 0) atomicAdd(&lsum[row], rs);
            }
    }
    grid.sync();

    // ---- phase 3: out split-K x4 (1024 tiles, XCD-friendly decode) ----
    for (int t = blockIdx.x; t < 1024; t += nb) {
        const int xt = t >> 7;
        const int yz = t & 127;
        const int yt = yz >> 2;
        const int zt = yz & 3;
        const int rowBase = yt * 128;
        const int colBase = xt * 128;
        const int kBeg = zt * 1024;

        f32x4 acc[4][4];
#pragma unroll
        for (int i = 0; i < 4; ++i)
#pragma unroll
            for (int j = 0; j < 4; ++j)
                acc[i][j] = (f32x4){0.f, 0.f, 0.f, 0.f};

        gemm_core_pf(P, vtb, 4096, rowBase, colBase, kBeg, kBeg + 1024, ldsA, ldsB, acc);

        const int orow0 = rowBase + (wave >> 1) * 64 + quad * 4;
        const int ocol0 = colBase + (wave & 1) * 64 + r;
#pragma unroll
        for (int i = 0; i < 4; ++i)
#pragma unroll
            for (int e = 0; e < 4; ++e) {
                const int row = orow0 + i * 16 + e;
#pragma unroll
                for (int j = 0; j < 4; ++j) {
                    const int col = ocol0 + j * 16;
                    if (useParts) {
                        unsigned short* pz = parts + (size_t)zt * (4096 * 1024);
                        pz[(long)row * 1024 + col] = f32_to_bf16(acc[i][j][e]);
                    } else {
                        atomicAdd(&Out[(long)row * 1024 + col], acc[i][j][e]);
                    }
                }
            }
    }
    grid.sync();

    // ---- phase 4: reduce + normalize ----
    if (useParts) {
        const size_t stride = (size_t)(4096 * 1024) / 4;
        for (int i = blockIdx.x * 256 + tid; i < 1024 * 1024; i += nb * 256) {
            const float inv = 1.0f / lsum[i >> 8];
            ushort4 a = ((const ushort4*)parts)[i];
            ushort4 b = ((const ushort4*)parts)[i + stride];
            ushort4 c = ((const ushort4*)parts)[i + 2 * stride];
            ushort4 d = ((const ushort4*)parts)[i + 3 * stride];
            float4 o;
            o.x = (bf16_to_f32(a.x) + bf16_to_f32(b.x) + bf16_to_f32(c.x) + bf16_to_f32(d.x)) * inv;
            o.y = (bf16_to_f32(a.y) + bf16_to_f32(b.y) + bf16_to_f32(c.y) + bf16_to_f32(d.y)) * inv;
            o.z = (bf16_to_f32(a.z) + bf16_to_f32(b.z) + bf16_to_f32(c.z) + bf16_to_f32(d.z)) * inv;
            o.w = (bf16_to_f32(a.w) + bf16_to_f32(b.w) + bf16_to_f32(c.w) + bf16_to_f32(d.w)) * inv;
            ((float4*)Out)[i] = o;
        }
    } else {
        for (int i = blockIdx.x * 256 + tid; i < 1024 * 1024; i += nb * 256) {
            const float inv = 1.0f / lsum[i >> 8];
            float4 v = ((const float4*)Out)[i];
            v.x *= inv; v.y *= inv; v.z *= inv; v.w *= inv;
            ((float4*)Out)[i] = v;
        }
    }
}

// ================= R7 fallback kernels (used only if cooperative launch fails) =================
__global__ __launch_bounds__(256) void cast_all(
    const float* __restrict__ x,  const float* __restrict__ y,
    const float* __restrict__ wq, const float* __restrict__ wk, const float* __restrict__ wv,
    unsigned short* __restrict__ xb,  unsigned short* __restrict__ yb,
    unsigned short* __restrict__ wqb, unsigned short* __restrict__ wkb,
    unsigned short* __restrict__ wvb, float* __restrict__ lsum)
{
    int b = blockIdx.x;
    if (b >= 11264) {
        float4 z = {0.f, 0.f, 0.f, 0.f};
#pragma unroll
        for (int t = 0; t < 4; ++t)
            ((float4*)lsum)[threadIdx.x * 4 + t] = z;
        return;
    }
    const float* s; unsigned short* d; int base;
    if      (b < 4096)  { s = x;  d = xb;  base = b; }
    else if (b < 8192)  { s = y;  d = yb;  base = b - 4096; }
    else if (b < 9216)  { s = wq; d = wqb; base = b - 8192; }
    else if (b < 10240) { s = wk; d = wkb; base = b - 9216; }
    else                { s = wv; d = wvb; base = b - 10240; }
    int i = base * 256 + threadIdx.x;
    float4 v = ((const float4*)s)[i];
    ushort4 o;
    o.x = f32_to_bf16(v.x);
    o.y = f32_to_bf16(v.y);
    o.z = f32_to_bf16(v.z);
    o.w = f32_to_bf16(v.w);
    ((ushort4*)d)[i] = o;
}

__global__ __launch_bounds__(256, 2)
void proj_batched(const unsigned short* __restrict__ xb, const unsigned short* __restrict__ yb,
                  const unsigned short* __restrict__ wqb, const unsigned short* __restrict__ wkb,
                  const unsigned short* __restrict__ wvb,
                  unsigned short* __restrict__ q, unsigned short* __restrict__ k,
                  unsigned short* __restrict__ vt,
                  const float* __restrict__ bq, const float* __restrict__ bk,
                  const float* __restrict__ bv)
{
    __shared__ __align__(16) unsigned short ldsA[2 * 128 * 32];
    __shared__ __align__(16) unsigned short ldsB[2 * 128 * 32];

    const int b = blockIdx.x;
    const int z = b >> 8;
    const int rb = b & 255;

    const unsigned short *A, *B;
    unsigned short* C;
    const float* bias;
    int N, rowBase, colBase;
    bool biasPerRow;
    if (z == 0) {
        A = xb; B = wqb; C = q; bias = bq; N = 1024; biasPerRow = false;
        colBase = (rb >> 5) * 128; rowBase = (rb & 31) * 128;
    } else if (z == 1) {
        A = yb; B = wkb; C = k; bias = bk; N = 1024; biasPerRow = false;
        colBase = (rb >> 5) * 128; rowBase = (rb & 31) * 128;
    } else {
        A = wvb; B = yb; C = vt; bias = bv; N = 4096; biasPerRow = true;
        colBase = (rb >> 3) * 128; rowBase = (rb & 7) * 128;
    }

    f32x4 acc[4][4];
#pragma unroll
    for (int i = 0; i < 4; ++i)
#pragma unroll
        for (int j = 0; j < 4; ++j)
            acc[i][j] = (f32x4){0.f, 0.f, 0.f, 0.f};

    gemm_core_pf(A, B, 1024, rowBase, colBase, 0, 1024, ldsA, ldsB, acc);

    const int lane = threadIdx.x & 63;
    const int wave = threadIdx.x >> 6;
    const int quad = lane >> 4;
    const int r    = lane & 15;
    const int orow0 = rowBase + (wave >> 1) * 64 + quad * 4;
    const int ocol0 = colBase + (wave & 1) * 64 + r;

#pragma unroll
    for (int i = 0; i < 4; ++i)
#pragma unroll
        for (int e = 0; e < 4; ++e) {
            const int row = orow0 + i * 16 + e;
            const float brow = biasPerRow ? bias[row] : 0.f;
#pragma unroll
            for (int j = 0; j < 4; ++j) {
                const int col = ocol0 + j * 16;
                const float bb = biasPerRow ? brow : bias[col];
                C[(long)row * N + col] = f32_to_bf16(acc[i][j][e] + bb);
            }
        }
}

__global__ __launch_bounds__(256, 2)
void scores_gemm(const unsigned short* __restrict__ q, const unsigned short* __restrict__ k,
                 unsigned short* __restrict__ P, float* __restrict__ lsum, float scale2)
{
    __shared__ __align__(16) unsigned short ldsA[2 * 128 * 32];
    __shared__ __align__(16) unsigned short ldsB[2 * 128 * 32];

    const int rowBase = blockIdx.y * 128;
    const int colBase = blockIdx.x * 128;

    f32x4 acc[4][4];
#pragma unroll
    for (int i = 0; i < 4; ++i)
#pragma unroll
        for (int j = 0; j < 4; ++j)
            acc[i][j] = (f32x4){0.f, 0.f, 0.f, 0.f};

    gemm_core_pf(q, k, 1024, rowBase, colBase, 0, 1024, ldsA, ldsB, acc);

    const int lane = threadIdx.x & 63;
    const int wave = threadIdx.x >> 6;
    const int quad = lane >> 4;
    const int r    = lane & 15;
    const int orow0 = rowBase + (wave >> 1) * 64 + quad * 4;
    const int ocol0 = colBase + (wave & 1) * 64 + r;

#pragma unroll
    for (int i = 0; i < 4; ++i)
#pragma unroll
        for (int e = 0; e < 4; ++e) {
            const int row = orow0 + i * 16 + e;
            float rs = 0.f;
#pragma unroll
            for (int j = 0; j < 4; ++j) {
                const int col = ocol0 + j * 16;
                const float p = exp2f(acc[i][j][e] * scale2);
                rs += p;
                P[(long)row * 4096 + col] = f32_to_bf16(p);
            }
#pragma unroll
            for (int m = 1; m < 16; m <<= 1) rs += __shfl_xor(rs, m, 64);
            if (r == 0) atomicAdd(&lsum[row], rs);
        }
}

template <int ATOMIC>
__global__ __launch_bounds__(256, 2)
void out_gemm_splitk(const unsigned short* __restrict__ P, const unsigned short* __restrict__ vt,
                     void* __restrict__ Out)
{
    __shared__ __align__(16) unsigned short ldsA[2 * 128 * 32];
    __shared__ __align__(16) unsigned short ldsB[2 * 128 * 32];

    const int bid = blockIdx.x;
    const int xt  = bid >> 7;
    const int yz  = bid & 127;
    const int yt  = yz >> 2;
    const int zt  = yz & 3;

    const int rowBase = yt * 128;
    const int colBase = xt * 128;
    const int kBeg = zt * 1024;

    f32x4 acc[4][4];
#pragma unroll
    for (int i = 0; i < 4; ++i)
#pragma unroll
        for (int j = 0; j < 4; ++j)
            acc[i][j] = (f32x4){0.f, 0.f, 0.f, 0.f};

    gemm_core_pf(P, vt, 4096, rowBase, colBase, kBeg, kBeg + 1024, ldsA, ldsB, acc);

    const int lane = threadIdx.x & 63;
    const int wave = threadIdx.x >> 6;
    const int quad = lane >> 4;
    const int r    = lane & 15;
    const int orow0 = rowBase + (wave >> 1) * 64 + quad * 4;
    const int ocol0 = colBase + (wave & 1) * 64 + r;

#pragma unroll
    for (int i = 0; i < 4; ++i)
#pragma unroll
        for (int e = 0; e < 4; ++e) {
            const int row = orow0 + i * 16 + e;
#pragma unroll
            for (int j = 0; j < 4; ++j) {
                const int col = ocol0 + j * 16;
                if (ATOMIC) {
                    atomicAdd(&((float*)Out)[(long)row * 1024 + col], acc[i][j][e]);
                } else {
                    unsigned short* parts = (unsigned short*)Out + (size_t)zt * (4096 * 1024);
                    parts[(long)row * 1024 + col] = f32_to_bf16(acc[i][j][e]);
                }
            }
        }
}

__global__ __launch_bounds__(256) void reduce_norm(const unsigned short* __restrict__ parts,
                                                   const float* __restrict__ lsum,
                                                   float* __restrict__ O) {
    const int i = blockIdx.x * 256 + threadIdx.x;
    const float inv = 1.0f / lsum[i >> 8];
    const size_t stride = (size_t)(4096 * 1024) / 4;
    ushort4 a = ((const ushort4*)parts)[i];
    ushort4 b = ((const ushort4*)parts)[i + stride];
    ushort4 c = ((const ushort4*)parts)[i + 2 * stride];
    ushort4 d = ((const ushort4*)parts)[i + 3 * stride];
    float4 o;
    o.x = (bf16_to_f32(a.x) + bf16_to_f32(b.x) + bf16_to_f32(c.x) + bf16_to_f32(d.x)) * inv;
    o.y = (bf16_to_f32(a.y) + bf16_to_f32(b.y) + bf16_to_f32(c.y) + bf16_to_f32(d.y)) * inv;
    o.z = (bf16_to_f32(a.z) + bf16_to_f32(b.z) + bf16_to_f32(c.z) + bf16_to_f32(d.z)) * inv;
    o.w = (bf16_to_f32(a.w) + bf16_to_f32(b.w) + bf16_to_f32(c.w) + bf16_to_f32(d.w)) * inv;
    ((float4*)O)[i] = o;
}

__global__ __launch_bounds__(256) void norm_rows(float* __restrict__ O, const float* __restrict__ lsum) {
    int i = blockIdx.x * 256 + threadIdx.x;
    const float inv = 1.0f / lsum[i >> 8];
    float4 v = ((const float4*)O)[i];
    v.x *= inv; v.y *= inv; v.z *= inv; v.w *= inv;
    ((float4*)O)[i] = v;
}

extern "C" void kernel_launch(void* const* d_in, const int* in_sizes, int n_in,
                              void* d_out, int out_size, void* d_ws, size_t ws_size,
                              hipStream_t stream) {
    const float* x  = (const float*)d_in[0];
    const float* y  = (const float*)d_in[1];
    const float* Wq = (const float*)d_in[2];
    const float* bq = (const float*)d_in[3];
    const float* Wk = (const float*)d_in[4];
    const float* bk = (const float*)d_in[5];
    const float* Wv = (const float*)d_in[6];
    const float* bv = (const float*)d_in[7];

    constexpr int Nx = 4096, Ny = 4096, H = 1024, Dv = 1024, Kin = 1024;

    char* ws = (char*)d_ws;
    size_t off = 0;
    auto carve = [&](size_t bytes) {
        char* p = ws + off;
        off += (bytes + 255) & ~(size_t)255;
        return p;
    };

    unsigned short* q_bf  = (unsigned short*)carve((size_t)Nx * H * 2);   // 8 MB
    unsigned short* k_bf  = (unsigned short*)carve((size_t)Ny * H * 2);   // 8 MB
    unsigned short* vt_bf = (unsigned short*)carve((size_t)Dv * Ny * 2);  // 8 MB
    float*          lsum  = (float*)carve((size_t)Nx * sizeof(float));    // 16 KB

    char* overlay = ws + off;
    unsigned short* x_bf  = (unsigned short*)overlay;
    unsigned short* y_bf  = x_bf  + (size_t)Nx * Kin;
    unsigned short* Wq_bf = y_bf  + (size_t)Ny * Kin;
    unsigned short* Wk_bf = Wq_bf + (size_t)H  * Kin;
    unsigned short* Wv_bf = Wk_bf + (size_t)H  * Kin;
    unsigned short* P_bf  = (unsigned short*)overlay;  // [Nx, Ny] bf16, phase 2+

    const size_t overlay_bytes = (size_t)Nx * Ny * 2;                 // 32 MB
    unsigned short* parts = (unsigned short*)(overlay + overlay_bytes);
    const size_t need_parts = (overlay + overlay_bytes + 4 * (size_t)Nx * Dv * 2) - ws;
    int useParts = (ws_size >= need_parts) ? 1 : 0;
    float* Out = (float*)d_out;

    // grid sizing for cooperative launch: all blocks must be co-resident
    int blocksPerCU = 0;
    hipError_t qerr = hipOccupancyMaxActiveBlocksPerMultiprocessor(
        &blocksPerCU, (const void*)fused_all, 256, 0);
    if (qerr != hipSuccess || blocksPerCU < 1) blocksPerCU = 2;  // conservative
    if (blocksPerCU > 4) blocksPerCU = 4;
    int nblocks = 256 * blocksPerCU;
    if (nblocks > 1024) nblocks = 1024;

    void* args[] = { &x, &y, &Wq, &Wk, &Wv, &bq, &bk, &bv,
                     &x_bf, &y_bf, &Wq_bf, &Wk_bf, &Wv_bf,
                     &q_bf, &k_bf, &vt_bf,
                     &P_bf, &parts, &lsum, &Out, &useParts };

    hipError_t lerr = hipLaunchCooperativeKernel(
        (const void*)fused_all, dim3(nblocks), dim3(256), args, 0, stream);

    if (lerr != hipSuccess) {
        // -------- fallback: proven R7 multi-kernel path --------
        if (!useParts)
            hipMemsetAsync(d_out, 0, (size_t)Nx * Dv * sizeof(float), stream);
        cast_all<<<11265, 256, 0, stream>>>(x, y, Wq, Wk, Wv, x_bf, y_bf, Wq_bf, Wk_bf, Wv_bf, lsum);
        proj_batched<<<768, 256, 0, stream>>>(x_bf, y_bf, Wq_bf, Wk_bf, Wv_bf,
                                              q_bf, k_bf, vt_bf, bq, bk, bv);
        const float scale2 = 1.4426950408889634f / 32.0f;
        scores_gemm<<<dim3(Ny / 128, Nx / 128), 256, 0, stream>>>(q_bf, k_bf, P_bf, lsum, scale2);
        if (useParts) {
            out_gemm_splitk<0><<<1024, 256, 0, stream>>>(P_bf, vt_bf, parts);
            reduce_norm<<<Nx * Dv / 4 / 256, 256, 0, stream>>>(parts, lsum, (float*)d_out);
        } else {
            out_gemm_splitk<1><<<1024, 256, 0, stream>>>(P_bf, vt_bf, d_out);
            norm_rows<<<Nx * Dv / 4 / 256, 256, 0, stream>>>((float*)d_out, lsum);
        }
    }
}

// Round 9
// 487.591 us; speedup vs baseline: 1.1487x; 1.1487x over previous
//
#include <hip/hip_runtime.h>
#include <cstdint>
#include <cstddef>

// ---------- types ----------
typedef __attribute__((ext_vector_type(8))) __bf16 bf16x8;   // MFMA A/B frag (4 VGPRs)
typedef __attribute__((ext_vector_type(4))) float  f32x4;    // MFMA C/D frag

__device__ __forceinline__ unsigned short f32_to_bf16(float f) {
    union { float f; unsigned int u; } cv;
    cv.f = f;
    unsigned int u = cv.u;
    return (unsigned short)((u + 0x7fffu + ((u >> 16) & 1u)) >> 16);  // RNE
}

__device__ __forceinline__ float bf16_to_f32(unsigned short h) {
    union { unsigned int u; float f; } cv;
    cv.u = ((unsigned int)h) << 16;
    return cv.f;
}

// async global->LDS, 16 bytes per lane. LDS dest is wave-uniform base + lane*16.
__device__ __forceinline__ void async_copy16(const unsigned short* g, unsigned short* lds) {
    __builtin_amdgcn_global_load_lds(
        (const __attribute__((address_space(1))) unsigned int*)g,
        (__attribute__((address_space(3))) unsigned int*)lds,
        16, 0, 0);
}

// ---------- fused fp32 -> bf16 cast for all five inputs + lsum/cnt zeroing ----------
__global__ __launch_bounds__(256) void cast_all(
    const float* __restrict__ x,  const float* __restrict__ y,
    const float* __restrict__ wq, const float* __restrict__ wk, const float* __restrict__ wv,
    unsigned short* __restrict__ xb,  unsigned short* __restrict__ yb,
    unsigned short* __restrict__ wqb, unsigned short* __restrict__ wkb,
    unsigned short* __restrict__ wvb, float* __restrict__ lsum, int* __restrict__ cnt)
{
    int b = blockIdx.x;
    if (b >= 11264) {   // last block: zero lsum[4096] and cnt[256]
        float4 z = {0.f, 0.f, 0.f, 0.f};
#pragma unroll
        for (int t = 0; t < 4; ++t)
            ((float4*)lsum)[threadIdx.x * 4 + t] = z;
        if (threadIdx.x < 64) ((int4*)cnt)[threadIdx.x] = (int4){0, 0, 0, 0};
        return;
    }
    const float* s; unsigned short* d; int base;
    if      (b < 4096)  { s = x;  d = xb;  base = b; }
    else if (b < 8192)  { s = y;  d = yb;  base = b - 4096; }
    else if (b < 9216)  { s = wq; d = wqb; base = b - 8192; }
    else if (b < 10240) { s = wk; d = wkb; base = b - 9216; }
    else                { s = wv; d = wvb; base = b - 10240; }
    int i = base * 256 + threadIdx.x;
    float4 v = ((const float4*)s)[i];
    ushort4 o;
    o.x = f32_to_bf16(v.x);
    o.y = f32_to_bf16(v.y);
    o.z = f32_to_bf16(v.z);
    o.w = f32_to_bf16(v.w);
    ((ushort4*)d)[i] = o;
}

// ---------- prefetch double-buffered GEMM core, BK=32 (R4 proven) ----------
// acc += A[rowBase:+128, kBeg:kEnd] @ B[colBase:+128, kBeg:kEnd]^T
// Tile s+1 issued into buf^1 BEFORE computing tile s; one barrier per step.
__device__ __forceinline__ void gemm_core_pf(
    const unsigned short* __restrict__ A, const unsigned short* __restrict__ B,
    int K, int rowBase, int colBase, int kBeg, int kEnd,
    unsigned short* ldsA, unsigned short* ldsB, f32x4 acc[4][4])
{
    const int tid  = threadIdx.x;
    const int lane = tid & 63;
    const int wave = tid >> 6;
    const int quad = lane >> 4;
    const int r    = lane & 15;
    const int wm   = wave >> 1;
    const int wn   = wave & 1;

    const int c1 = tid + 256;
    const long aOff0 = (long)(rowBase + (tid >> 2)) * K + (tid & 3) * 8;
    const long aOff1 = (long)(rowBase + (c1  >> 2)) * K + (c1  & 3) * 8;
    const long bOff0 = (long)(colBase + (tid >> 2)) * K + (tid & 3) * 8;
    const long bOff1 = (long)(colBase + (c1  >> 2)) * K + (c1  & 3) * 8;
    unsigned short* ldsA0 = ldsA + tid * 8;
    unsigned short* ldsA1 = ldsA + c1 * 8;
    unsigned short* ldsB0 = ldsB + tid * 8;
    unsigned short* ldsB1 = ldsB + c1 * 8;

    const int aReadOff = (wm * 64 + r) * 32 + quad * 8;
    const int bReadOff = (wn * 64 + r) * 32 + quad * 8;

    const int nSteps = (kEnd - kBeg) >> 5;

    // prologue: tile 0 -> buffer 0
    async_copy16(A + aOff0 + kBeg, ldsA0);
    async_copy16(A + aOff1 + kBeg, ldsA1);
    async_copy16(B + bOff0 + kBeg, ldsB0);
    async_copy16(B + bOff1 + kBeg, ldsB1);

    for (int s = 0; s < nSteps; ++s) {
        const int cur = (s & 1) << 12;          // 0 or 4096 elems
        const int nxt = cur ^ 4096;
        __builtin_amdgcn_s_waitcnt(0);          // tile s arrived
        __syncthreads();                        // visible to all; buf[nxt] free
        if (s + 1 < nSteps) {
            const int kn = kBeg + ((s + 1) << 5);
            async_copy16(A + aOff0 + kn, ldsA0 + nxt);
            async_copy16(A + aOff1 + kn, ldsA1 + nxt);
            async_copy16(B + bOff0 + kn, ldsB0 + nxt);
            async_copy16(B + bOff1 + kn, ldsB1 + nxt);
        }
        bf16x8 af[4], bfr[4];
#pragma unroll
        for (int i = 0; i < 4; ++i)
            af[i] = *(const bf16x8*)(ldsA + cur + aReadOff + i * 16 * 32);
#pragma unroll
        for (int j = 0; j < 4; ++j)
            bfr[j] = *(const bf16x8*)(ldsB + cur + bReadOff + j * 16 * 32);
#pragma unroll
        for (int i = 0; i < 4; ++i)
#pragma unroll
            for (int j = 0; j < 4; ++j)
                acc[i][j] = __builtin_amdgcn_mfma_f32_16x16x32_bf16(af[i], bfr[j], acc[i][j], 0, 0, 0);
    }
}

// ---------- batched projections: 768 blocks (3 problems x 256), K=1024 ----------
__global__ __launch_bounds__(256, 2)
void proj_batched(const unsigned short* __restrict__ xb, const unsigned short* __restrict__ yb,
                  const unsigned short* __restrict__ wqb, const unsigned short* __restrict__ wkb,
                  const unsigned short* __restrict__ wvb,
                  unsigned short* __restrict__ q, unsigned short* __restrict__ k,
                  unsigned short* __restrict__ vt,
                  const float* __restrict__ bq, const float* __restrict__ bk,
                  const float* __restrict__ bv)
{
    __shared__ __align__(16) unsigned short ldsA[2 * 128 * 32];
    __shared__ __align__(16) unsigned short ldsB[2 * 128 * 32];

    const int b = blockIdx.x;
    const int z = b >> 8;
    const int rb = b & 255;

    const unsigned short *A, *B;
    unsigned short* C;
    const float* bias;
    int N, rowBase, colBase;
    bool biasPerRow;
    if (z == 0) {
        A = xb; B = wqb; C = q; bias = bq; N = 1024; biasPerRow = false;
        colBase = (rb >> 5) * 128; rowBase = (rb & 31) * 128;   // bid%8 = rowTile%8
    } else if (z == 1) {
        A = yb; B = wkb; C = k; bias = bk; N = 1024; biasPerRow = false;
        colBase = (rb >> 5) * 128; rowBase = (rb & 31) * 128;
    } else {
        A = wvb; B = yb; C = vt; bias = bv; N = 4096; biasPerRow = true;
        colBase = (rb >> 3) * 128; rowBase = (rb & 7) * 128;    // bid%8 = rowTile
    }

    f32x4 acc[4][4];
#pragma unroll
    for (int i = 0; i < 4; ++i)
#pragma unroll
        for (int j = 0; j < 4; ++j)
            acc[i][j] = (f32x4){0.f, 0.f, 0.f, 0.f};

    gemm_core_pf(A, B, 1024, rowBase, colBase, 0, 1024, ldsA, ldsB, acc);

    const int lane = threadIdx.x & 63;
    const int wave = threadIdx.x >> 6;
    const int quad = lane >> 4;
    const int r    = lane & 15;
    const int orow0 = rowBase + (wave >> 1) * 64 + quad * 4;
    const int ocol0 = colBase + (wave & 1) * 64 + r;

#pragma unroll
    for (int i = 0; i < 4; ++i)
#pragma unroll
        for (int e = 0; e < 4; ++e) {
            const int row = orow0 + i * 16 + e;
            const float brow = biasPerRow ? bias[row] : 0.f;
#pragma unroll
            for (int j = 0; j < 4; ++j) {
                const int col = ocol0 + j * 16;
                const float bb = biasPerRow ? brow : bias[col];
                C[(long)row * N + col] = f32_to_bf16(acc[i][j][e] + bb);
            }
        }
}

// ---------- scores: P = exp2(scale2 * (q @ k^T)) bf16, lsum[row] += rowsum ----------
__global__ __launch_bounds__(256, 2)
void scores_gemm(const unsigned short* __restrict__ q, const unsigned short* __restrict__ k,
                 unsigned short* __restrict__ P, float* __restrict__ lsum, float scale2)
{
    __shared__ __align__(16) unsigned short ldsA[2 * 128 * 32];
    __shared__ __align__(16) unsigned short ldsB[2 * 128 * 32];

    const int rowBase = blockIdx.y * 128;
    const int colBase = blockIdx.x * 128;

    f32x4 acc[4][4];
#pragma unroll
    for (int i = 0; i < 4; ++i)
#pragma unroll
        for (int j = 0; j < 4; ++j)
            acc[i][j] = (f32x4){0.f, 0.f, 0.f, 0.f};

    gemm_core_pf(q, k, 1024, rowBase, colBase, 0, 1024, ldsA, ldsB, acc);

    const int lane = threadIdx.x & 63;
    const int wave = threadIdx.x >> 6;
    const int quad = lane >> 4;
    const int r    = lane & 15;
    const int orow0 = rowBase + (wave >> 1) * 64 + quad * 4;
    const int ocol0 = colBase + (wave & 1) * 64 + r;

#pragma unroll
    for (int i = 0; i < 4; ++i)
#pragma unroll
        for (int e = 0; e < 4; ++e) {
            const int row = orow0 + i * 16 + e;
            float rs = 0.f;
#pragma unroll
            for (int j = 0; j < 4; ++j) {
                const int col = ocol0 + j * 16;
                const float p = exp2f(acc[i][j][e] * scale2);
                rs += p;
                P[(long)row * 4096 + col] = f32_to_bf16(p);
            }
#pragma unroll
            for (int m = 1; m < 16; m <<= 1) rs += __shfl_xor(rs, m, 64);
            if (r == 0) atomicAdd(&lsum[row], rs);
        }
}

// ---------- output GEMM, split-K x4, fused finisher ----------
// 1D grid 1024: bid = x*128 + y*4 + z -> bid%8 invariant in x (P row-strip sharing per XCD).
// ATOMIC=0: store bf16 partial z into parts; fence; count; 4th arriver reduces the
//           4 partials + normalizes by lsum -> Out (no separate reduce kernel).
// ATOMIC=1: fp32 atomicAdd into Out (fallback when ws too small; norm_rows after).
template <int ATOMIC>
__global__ __launch_bounds__(256, 2)
void out_gemm_splitk(const unsigned short* __restrict__ P, const unsigned short* __restrict__ vt,
                     unsigned short* __restrict__ parts, int* __restrict__ cnt,
                     const float* __restrict__ lsum, float* __restrict__ Out)
{
    __shared__ __align__(16) unsigned short ldsA[2 * 128 * 32];
    __shared__ __align__(16) unsigned short ldsB[2 * 128 * 32];

    const int bid = blockIdx.x;
    const int xt  = bid >> 7;          // 0..7  (output col tile)
    const int yz  = bid & 127;
    const int yt  = yz >> 2;           // 0..31 (output row tile)
    const int zt  = yz & 3;            // 0..3  (k split)

    const int rowBase = yt * 128;
    const int colBase = xt * 128;
    const int kBeg = zt * 1024;

    f32x4 acc[4][4];
#pragma unroll
    for (int i = 0; i < 4; ++i)
#pragma unroll
        for (int j = 0; j < 4; ++j)
            acc[i][j] = (f32x4){0.f, 0.f, 0.f, 0.f};

    gemm_core_pf(P, vt, 4096, rowBase, colBase, kBeg, kBeg + 1024, ldsA, ldsB, acc);

    const int lane = threadIdx.x & 63;
    const int wave = threadIdx.x >> 6;
    const int quad = lane >> 4;
    const int r    = lane & 15;
    const int orow0 = rowBase + (wave >> 1) * 64 + quad * 4;
    const int ocol0 = colBase + (wave & 1) * 64 + r;

    if (ATOMIC) {
#pragma unroll
        for (int i = 0; i < 4; ++i)
#pragma unroll
            for (int e = 0; e < 4; ++e) {
                const int row = orow0 + i * 16 + e;
#pragma unroll
                for (int j = 0; j < 4; ++j)
                    atomicAdd(&Out[(long)row * 1024 + ocol0 + j * 16], acc[i][j][e]);
            }
        return;
    }

    // store bf16 partial for this z-split
    unsigned short* pz = parts + (size_t)zt * (4096 * 1024);
#pragma unroll
    for (int i = 0; i < 4; ++i)
#pragma unroll
        for (int e = 0; e < 4; ++e) {
            const int row = orow0 + i * 16 + e;
#pragma unroll
            for (int j = 0; j < 4; ++j)
                pz[(long)row * 1024 + ocol0 + j * 16] = f32_to_bf16(acc[i][j][e]);
        }

    // fence + count; last arriver reduces this 128x128 tile
    __threadfence();                                  // release partial stores (device scope)
    __shared__ int lastFlag;
    if (threadIdx.x == 0)
        lastFlag = atomicAdd(&cnt[yt * 8 + xt], 1);   // device-scope by default [m20]
    __syncthreads();
    if (lastFlag != 3) return;
    __threadfence();                                  // acquire other blocks' stores

    const size_t zs = (size_t)4096 * 1024;
    for (int it = threadIdx.x; it < 4096; it += 256) {       // 4096 ushort4 groups per tile
        const int row = rowBase + (it >> 5);
        const size_t base = (size_t)row * 1024 + colBase + ((it & 31) << 2);
        const float inv = 1.0f / lsum[row];
        float s0 = 0.f, s1 = 0.f, s2 = 0.f, s3 = 0.f;
#pragma unroll
        for (int z = 0; z < 4; ++z) {
            ushort4 a = *(const ushort4*)(parts + z * zs + base);
            s0 += bf16_to_f32(a.x); s1 += bf16_to_f32(a.y);
            s2 += bf16_to_f32(a.z); s3 += bf16_to_f32(a.w);
        }
        float4 o = {s0 * inv, s1 * inv, s2 * inv, s3 * inv};
        *(float4*)(&Out[base]) = o;
    }
}

// ---------- normalize in place (atomic fallback path) ----------
__global__ __launch_bounds__(256) void norm_rows(float* __restrict__ O, const float* __restrict__ lsum) {
    int i = blockIdx.x * 256 + threadIdx.x;
    const float inv = 1.0f / lsum[i >> 8];
    float4 v = ((const float4*)O)[i];
    v.x *= inv; v.y *= inv; v.z *= inv; v.w *= inv;
    ((float4*)O)[i] = v;
}

extern "C" void kernel_launch(void* const* d_in, const int* in_sizes, int n_in,
                              void* d_out, int out_size, void* d_ws, size_t ws_size,
                              hipStream_t stream) {
    const float* x  = (const float*)d_in[0];
    const float* y  = (const float*)d_in[1];
    const float* Wq = (const float*)d_in[2];
    const float* bq = (const float*)d_in[3];
    const float* Wk = (const float*)d_in[4];
    const float* bk = (const float*)d_in[5];
    const float* Wv = (const float*)d_in[6];
    const float* bv = (const float*)d_in[7];

    constexpr int Nx = 4096, Ny = 4096, H = 1024, Dv = 1024, Kin = 1024;

    char* ws = (char*)d_ws;
    size_t off = 0;
    auto carve = [&](size_t bytes) {
        char* p = ws + off;
        off += (bytes + 255) & ~(size_t)255;
        return p;
    };

    unsigned short* q_bf  = (unsigned short*)carve((size_t)Nx * H * 2);   // 8 MB
    unsigned short* k_bf  = (unsigned short*)carve((size_t)Ny * H * 2);   // 8 MB
    unsigned short* vt_bf = (unsigned short*)carve((size_t)Dv * Ny * 2);  // 8 MB
    float*          lsum  = (float*)carve((size_t)Nx * sizeof(float));    // 16 KB
    int*            cnt   = (int*)carve(256 * sizeof(int));               // 1 KB

    // overlay: phase 1 = bf16 casts (22 MB), phase 2 = P (32 MB)
    char* overlay = ws + off;
    unsigned short* x_bf  = (unsigned short*)overlay;
    unsigned short* y_bf  = x_bf  + (size_t)Nx * Kin;
    unsigned short* Wq_bf = y_bf  + (size_t)Ny * Kin;
    unsigned short* Wk_bf = Wq_bf + (size_t)H  * Kin;
    unsigned short* Wv_bf = Wk_bf + (size_t)H  * Kin;
    unsigned short* P_bf  = (unsigned short*)overlay;  // [Nx, Ny] bf16, phase 2

    // bf16 partials after the P region: 4 x 8 MB
    const size_t overlay_bytes = (size_t)Nx * Ny * 2;                 // 32 MB
    unsigned short* parts = (unsigned short*)(overlay + overlay_bytes);
    const size_t need_parts = (overlay + overlay_bytes + 4 * (size_t)Nx * Dv * 2) - ws;
    const bool useParts = ws_size >= need_parts;

    if (!useParts)
        hipMemsetAsync(d_out, 0, (size_t)Nx * Dv * sizeof(float), stream);

    // phase 0: all casts + lsum/cnt zeroing, one launch
    cast_all<<<11265, 256, 0, stream>>>(x, y, Wq, Wk, Wv, x_bf, y_bf, Wq_bf, Wk_bf, Wv_bf,
                                        lsum, cnt);

    // phase 1: all three projections, one launch (768 blocks = 3 blocks/CU)
    proj_batched<<<768, 256, 0, stream>>>(x_bf, y_bf, Wq_bf, Wk_bf, Wv_bf,
                                          q_bf, k_bf, vt_bf, bq, bk, bv);

    // phase 2a: P = exp(q k^T / 32), lsum row sums (1024 blocks = 4/CU)
    const float scale2 = 1.4426950408889634f / 32.0f;  // log2(e)/sqrt(H)
    scores_gemm<<<dim3(Ny / 128, Nx / 128), 256, 0, stream>>>(q_bf, k_bf, P_bf, lsum, scale2);

    // phase 2b: split-K x4 with fused fence+counter reduction (1024 blocks, XCD-swizzled)
    if (useParts) {
        out_gemm_splitk<0><<<1024, 256, 0, stream>>>(P_bf, vt_bf, parts, cnt, lsum, (float*)d_out);
    } else {
        out_gemm_splitk<1><<<1024, 256, 0, stream>>>(P_bf, vt_bf, nullptr, cnt, lsum, (float*)d_out);
        norm_rows<<<Nx * Dv / 4 / 256, 256, 0, stream>>>((float*)d_out, lsum);
    }
}

// Round 10
// 243.364 us; speedup vs baseline: 2.3015x; 2.0035x over previous
//
#include <hip/hip_runtime.h>
#include <cstdint>
#include <cstddef>

// ---------- types ----------
typedef __attribute__((ext_vector_type(8))) __bf16 bf16x8;   // MFMA A/B frag (4 VGPRs)
typedef __attribute__((ext_vector_type(4))) float  f32x4;    // MFMA C/D frag

__device__ __forceinline__ unsigned short f32_to_bf16(float f) {
    union { float f; unsigned int u; } cv;
    cv.f = f;
    unsigned int u = cv.u;
    return (unsigned short)((u + 0x7fffu + ((u >> 16) & 1u)) >> 16);  // RNE
}

__device__ __forceinline__ float bf16_to_f32(unsigned short h) {
    union { unsigned int u; float f; } cv;
    cv.u = ((unsigned int)h) << 16;
    return cv.f;
}

// async global->LDS, 16 bytes per lane. LDS dest is wave-uniform base + lane*16.
__device__ __forceinline__ void async_copy16(const unsigned short* g, unsigned short* lds) {
    __builtin_amdgcn_global_load_lds(
        (const __attribute__((address_space(1))) unsigned int*)g,
        (__attribute__((address_space(3))) unsigned int*)lds,
        16, 0, 0);
}

// ---------- prefetch double-buffered GEMM core, BK=32, bf16 sources (R4/R7 proven) ----------
// acc += A[rowBase:+128, kBeg:kEnd] @ B[colBase:+128, kBeg:kEnd]^T
// Tile s+1 issued into buf^1 BEFORE computing tile s; one barrier per step.
__device__ __forceinline__ void gemm_core_pf(
    const unsigned short* __restrict__ A, const unsigned short* __restrict__ B,
    int K, int rowBase, int colBase, int kBeg, int kEnd,
    unsigned short* ldsA, unsigned short* ldsB, f32x4 acc[4][4])
{
    const int tid  = threadIdx.x;
    const int lane = tid & 63;
    const int wave = tid >> 6;
    const int quad = lane >> 4;
    const int r    = lane & 15;
    const int wm   = wave >> 1;
    const int wn   = wave & 1;

    const int c1 = tid + 256;
    const long aOff0 = (long)(rowBase + (tid >> 2)) * K + (tid & 3) * 8;
    const long aOff1 = (long)(rowBase + (c1  >> 2)) * K + (c1  & 3) * 8;
    const long bOff0 = (long)(colBase + (tid >> 2)) * K + (tid & 3) * 8;
    const long bOff1 = (long)(colBase + (c1  >> 2)) * K + (c1  & 3) * 8;
    unsigned short* ldsA0 = ldsA + tid * 8;
    unsigned short* ldsA1 = ldsA + c1 * 8;
    unsigned short* ldsB0 = ldsB + tid * 8;
    unsigned short* ldsB1 = ldsB + c1 * 8;

    const int aReadOff = (wm * 64 + r) * 32 + quad * 8;
    const int bReadOff = (wn * 64 + r) * 32 + quad * 8;

    const int nSteps = (kEnd - kBeg) >> 5;

    // prologue: tile 0 -> buffer 0
    async_copy16(A + aOff0 + kBeg, ldsA0);
    async_copy16(A + aOff1 + kBeg, ldsA1);
    async_copy16(B + bOff0 + kBeg, ldsB0);
    async_copy16(B + bOff1 + kBeg, ldsB1);

    for (int s = 0; s < nSteps; ++s) {
        const int cur = (s & 1) << 12;          // 0 or 4096 elems
        const int nxt = cur ^ 4096;
        __builtin_amdgcn_s_waitcnt(0);          // tile s arrived
        __syncthreads();                        // visible to all; buf[nxt] free
        if (s + 1 < nSteps) {
            const int kn = kBeg + ((s + 1) << 5);
            async_copy16(A + aOff0 + kn, ldsA0 + nxt);
            async_copy16(A + aOff1 + kn, ldsA1 + nxt);
            async_copy16(B + bOff0 + kn, ldsB0 + nxt);
            async_copy16(B + bOff1 + kn, ldsB1 + nxt);
        }
        bf16x8 af[4], bfr[4];
#pragma unroll
        for (int i = 0; i < 4; ++i)
            af[i] = *(const bf16x8*)(ldsA + cur + aReadOff + i * 16 * 32);
#pragma unroll
        for (int j = 0; j < 4; ++j)
            bfr[j] = *(const bf16x8*)(ldsB + cur + bReadOff + j * 16 * 32);
#pragma unroll
        for (int i = 0; i < 4; ++i)
#pragma unroll
            for (int j = 0; j < 4; ++j)
                acc[i][j] = __builtin_amdgcn_mfma_f32_16x16x32_bf16(af[i], bfr[j], acc[i][j], 0, 0, 0);
    }
}

// ---------- batched projections from FP32 sources (cast fused into staging) ----------
// 768 blocks (3 problems x 256), K=1024.
// z=0: q  = x @ Wq^T + bq[col]   z=1: k = y @ Wk^T + bk[col]   z=2: vt = Wv @ y^T + bv[row]
// Staging: global float4 -> VGPR -> cvt bf16 -> ds_write_b64 into the same LDS layout
// as gemm_core_pf (row-major 128x32 per buffer). One barrier per step: writes to
// buf[s&1] at step s are separated from step s-2's reads by step s-1's barrier.
// Register prefetch of tile s+1 issued after the barrier, consumed at step s+1's cvt
// (no vmcnt drain at the barrier: all pending vm loads target registers).
// Block 0 additionally zeroes lsum[4096] (consumed only by the later scores dispatch).
__global__ __launch_bounds__(256, 2)
void proj_batched_f32(const float* __restrict__ x, const float* __restrict__ y,
                      const float* __restrict__ wq, const float* __restrict__ wk,
                      const float* __restrict__ wv,
                      unsigned short* __restrict__ q, unsigned short* __restrict__ k,
                      unsigned short* __restrict__ vt,
                      const float* __restrict__ bq, const float* __restrict__ bk,
                      const float* __restrict__ bv, float* __restrict__ lsum)
{
    __shared__ __align__(16) unsigned short ldsA[2 * 128 * 32];
    __shared__ __align__(16) unsigned short ldsB[2 * 128 * 32];

    const int b = blockIdx.x;
    const int tid = threadIdx.x;

    if (b == 0) {   // zero lsum (read only by the scores dispatch, after this one drains)
        float4 zz = {0.f, 0.f, 0.f, 0.f};
#pragma unroll
        for (int t = 0; t < 4; ++t)
            ((float4*)lsum)[tid * 4 + t] = zz;
    }

    const int z = b >> 8;
    const int rb = b & 255;

    const float *A, *B;
    unsigned short* C;
    const float* bias;
    int N, rowBase, colBase;
    bool biasPerRow;
    if (z == 0) {
        A = x; B = wq; C = q; bias = bq; N = 1024; biasPerRow = false;
        colBase = (rb >> 5) * 128; rowBase = (rb & 31) * 128;   // bid%8 = rowTile%8
    } else if (z == 1) {
        A = y; B = wk; C = k; bias = bk; N = 1024; biasPerRow = false;
        colBase = (rb >> 5) * 128; rowBase = (rb & 31) * 128;
    } else {
        A = wv; B = y; C = vt; bias = bv; N = 4096; biasPerRow = true;
        colBase = (rb >> 3) * 128; rowBase = (rb & 7) * 128;    // bid%8 = rowTile
    }

    f32x4 acc[4][4];
#pragma unroll
    for (int i = 0; i < 4; ++i)
#pragma unroll
        for (int j = 0; j < 4; ++j)
            acc[i][j] = (f32x4){0.f, 0.f, 0.f, 0.f};

    // ---- K-loop with fused fp32->bf16 staging ----
    // tile = 128 rows x 32 k (fp32). 1024 float4 groups; thread t handles f = t + 256*i.
    // f decode: row = f>>3, col4 = f&7 (8 float4 per 32-elem row). K/4 = 256 float4/row.
    const int lane = tid & 63;
    const int wave = tid >> 6;
    const int quad = lane >> 4;
    const int r    = lane & 15;
    const int aReadOff = ((wave >> 1) * 64 + r) * 32 + quad * 8;
    const int bReadOff = ((wave & 1) * 64 + r) * 32 + quad * 8;

    long gA[4], gB[4];
#pragma unroll
    for (int i = 0; i < 4; ++i) {
        const int f = tid + 256 * i;
        gA[i] = (long)(rowBase + (f >> 3)) * 256 + (f & 7);   // float4 index, +kt*8 per step
        gB[i] = (long)(colBase + (f >> 3)) * 256 + (f & 7);
    }

    float4 ra[4], rbv[4];
#pragma unroll
    for (int i = 0; i < 4; ++i) {
        ra[i]  = ((const float4*)A)[gA[i]];
        rbv[i] = ((const float4*)B)[gB[i]];
    }

    for (int s = 0; s < 32; ++s) {
        const int buf = (s & 1) << 12;          // elems offset: 0 / 4096
        // cvt + ds_write tile s (regs already waited-on by compiler at first use)
#pragma unroll
        for (int i = 0; i < 4; ++i) {
            ushort4 ua, ub;
            ua.x = f32_to_bf16(ra[i].x);  ua.y = f32_to_bf16(ra[i].y);
            ua.z = f32_to_bf16(ra[i].z);  ua.w = f32_to_bf16(ra[i].w);
            ub.x = f32_to_bf16(rbv[i].x); ub.y = f32_to_bf16(rbv[i].y);
            ub.z = f32_to_bf16(rbv[i].z); ub.w = f32_to_bf16(rbv[i].w);
            ((ushort4*)(ldsA + buf))[tid + 256 * i] = ua;
            ((ushort4*)(ldsB + buf))[tid + 256 * i] = ub;
        }
        __syncthreads();                        // writes visible; no vm loads pending here
        if (s + 1 < 32) {                       // prefetch tile s+1 -> regs (flies under MFMA)
            const int kt8 = (s + 1) * 8;
#pragma unroll
            for (int i = 0; i < 4; ++i) {
                ra[i]  = ((const float4*)A)[gA[i] + kt8];
                rbv[i] = ((const float4*)B)[gB[i] + kt8];
            }
        }
        bf16x8 af[4], bfr[4];
#pragma unroll
        for (int i = 0; i < 4; ++i)
            af[i] = *(const bf16x8*)(ldsA + buf + aReadOff + i * 16 * 32);
#pragma unroll
        for (int j = 0; j < 4; ++j)
            bfr[j] = *(const bf16x8*)(ldsB + buf + bReadOff + j * 16 * 32);
#pragma unroll
        for (int i = 0; i < 4; ++i)
#pragma unroll
            for (int j = 0; j < 4; ++j)
                acc[i][j] = __builtin_amdgcn_mfma_f32_16x16x32_bf16(af[i], bfr[j], acc[i][j], 0, 0, 0);
    }

    const int orow0 = rowBase + (wave >> 1) * 64 + quad * 4;
    const int ocol0 = colBase + (wave & 1) * 64 + r;

#pragma unroll
    for (int i = 0; i < 4; ++i)
#pragma unroll
        for (int e = 0; e < 4; ++e) {
            const int row = orow0 + i * 16 + e;
            const float brow = biasPerRow ? bias[row] : 0.f;
#pragma unroll
            for (int j = 0; j < 4; ++j) {
                const int col = ocol0 + j * 16;
                const float bb = biasPerRow ? brow : bias[col];
                C[(long)row * N + col] = f32_to_bf16(acc[i][j][e] + bb);
            }
        }
}

// ---------- scores: P = exp2(scale2 * (q @ k^T)) bf16, lsum[row] += rowsum ----------
__global__ __launch_bounds__(256, 2)
void scores_gemm(const unsigned short* __restrict__ q, const unsigned short* __restrict__ k,
                 unsigned short* __restrict__ P, float* __restrict__ lsum, float scale2)
{
    __shared__ __align__(16) unsigned short ldsA[2 * 128 * 32];
    __shared__ __align__(16) unsigned short ldsB[2 * 128 * 32];

    const int rowBase = blockIdx.y * 128;
    const int colBase = blockIdx.x * 128;

    f32x4 acc[4][4];
#pragma unroll
    for (int i = 0; i < 4; ++i)
#pragma unroll
        for (int j = 0; j < 4; ++j)
            acc[i][j] = (f32x4){0.f, 0.f, 0.f, 0.f};

    gemm_core_pf(q, k, 1024, rowBase, colBase, 0, 1024, ldsA, ldsB, acc);

    const int lane = threadIdx.x & 63;
    const int wave = threadIdx.x >> 6;
    const int quad = lane >> 4;
    const int r    = lane & 15;
    const int orow0 = rowBase + (wave >> 1) * 64 + quad * 4;
    const int ocol0 = colBase + (wave & 1) * 64 + r;

#pragma unroll
    for (int i = 0; i < 4; ++i)
#pragma unroll
        for (int e = 0; e < 4; ++e) {
            const int row = orow0 + i * 16 + e;
            float rs = 0.f;
#pragma unroll
            for (int j = 0; j < 4; ++j) {
                const int col = ocol0 + j * 16;
                const float p = exp2f(acc[i][j][e] * scale2);
                rs += p;
                P[(long)row * 4096 + col] = f32_to_bf16(p);
            }
#pragma unroll
            for (int m = 1; m < 16; m <<= 1) rs += __shfl_xor(rs, m, 64);
            if (r == 0) atomicAdd(&lsum[row], rs);
        }
}

// ---------- output GEMM, split-K x4 ----------
// 1D grid 1024: bid = x*128 + y*4 + z -> bid%8 invariant in x (P row-strip sharing per XCD).
// ATOMIC=0: store bf16 partial z into parts + z*8MB (plain coalesced stores).
// ATOMIC=1: fp32 atomicAdd into O (fallback when ws too small).
template <int ATOMIC>
__global__ __launch_bounds__(256, 2)
void out_gemm_splitk(const unsigned short* __restrict__ P, const unsigned short* __restrict__ vt,
                     void* __restrict__ Out)
{
    __shared__ __align__(16) unsigned short ldsA[2 * 128 * 32];
    __shared__ __align__(16) unsigned short ldsB[2 * 128 * 32];

    const int bid = blockIdx.x;
    const int xt  = bid >> 7;          // 0..7  (output col tile)
    const int yz  = bid & 127;
    const int yt  = yz >> 2;           // 0..31 (output row tile)
    const int zt  = yz & 3;            // 0..3  (k split)

    const int rowBase = yt * 128;
    const int colBase = xt * 128;
    const int kBeg = zt * 1024;

    f32x4 acc[4][4];
#pragma unroll
    for (int i = 0; i < 4; ++i)
#pragma unroll
        for (int j = 0; j < 4; ++j)
            acc[i][j] = (f32x4){0.f, 0.f, 0.f, 0.f};

    gemm_core_pf(P, vt, 4096, rowBase, colBase, kBeg, kBeg + 1024, ldsA, ldsB, acc);

    const int lane = threadIdx.x & 63;
    const int wave = threadIdx.x >> 6;
    const int quad = lane >> 4;
    const int r    = lane & 15;
    const int orow0 = rowBase + (wave >> 1) * 64 + quad * 4;
    const int ocol0 = colBase + (wave & 1) * 64 + r;

#pragma unroll
    for (int i = 0; i < 4; ++i)
#pragma unroll
        for (int e = 0; e < 4; ++e) {
            const int row = orow0 + i * 16 + e;
#pragma unroll
            for (int j = 0; j < 4; ++j) {
                const int col = ocol0 + j * 16;
                if (ATOMIC) {
                    atomicAdd(&((float*)Out)[(long)row * 1024 + col], acc[i][j][e]);
                } else {
                    unsigned short* parts = (unsigned short*)Out + (size_t)zt * (4096 * 1024);
                    parts[(long)row * 1024 + col] = f32_to_bf16(acc[i][j][e]);
                }
            }
        }
}

// ---------- reduce 4 bf16 partials + normalize: O = (P0+P1+P2+P3) / lsum[row] ----------
__global__ __launch_bounds__(256) void reduce_norm(const unsigned short* __restrict__ parts,
                                                   const float* __restrict__ lsum,
                                                   float* __restrict__ O) {
    const int i = blockIdx.x * 256 + threadIdx.x;   // ushort4/float4 group index; 256 per row
    const float inv = 1.0f / lsum[i >> 8];
    const size_t stride = (size_t)(4096 * 1024) / 4;   // ushort4 units
    ushort4 a = ((const ushort4*)parts)[i];
    ushort4 b = ((const ushort4*)parts)[i + stride];
    ushort4 c = ((const ushort4*)parts)[i + 2 * stride];
    ushort4 d = ((const ushort4*)parts)[i + 3 * stride];
    float4 o;
    o.x = (bf16_to_f32(a.x) + bf16_to_f32(b.x) + bf16_to_f32(c.x) + bf16_to_f32(d.x)) * inv;
    o.y = (bf16_to_f32(a.y) + bf16_to_f32(b.y) + bf16_to_f32(c.y) + bf16_to_f32(d.y)) * inv;
    o.z = (bf16_to_f32(a.z) + bf16_to_f32(b.z) + bf16_to_f32(c.z) + bf16_to_f32(d.z)) * inv;
    o.w = (bf16_to_f32(a.w) + bf16_to_f32(b.w) + bf16_to_f32(c.w) + bf16_to_f32(d.w)) * inv;
    ((float4*)O)[i] = o;
}

// ---------- normalize in place (atomic fallback path) ----------
__global__ __launch_bounds__(256) void norm_rows(float* __restrict__ O, const float* __restrict__ lsum) {
    int i = blockIdx.x * 256 + threadIdx.x;
    const float inv = 1.0f / lsum[i >> 8];
    float4 v = ((const float4*)O)[i];
    v.x *= inv; v.y *= inv; v.z *= inv; v.w *= inv;
    ((float4*)O)[i] = v;
}

extern "C" void kernel_launch(void* const* d_in, const int* in_sizes, int n_in,
                              void* d_out, int out_size, void* d_ws, size_t ws_size,
                              hipStream_t stream) {
    const float* x  = (const float*)d_in[0];
    const float* y  = (const float*)d_in[1];
    const float* Wq = (const float*)d_in[2];
    const float* bq = (const float*)d_in[3];
    const float* Wk = (const float*)d_in[4];
    const float* bk = (const float*)d_in[5];
    const float* Wv = (const float*)d_in[6];
    const float* bv = (const float*)d_in[7];

    constexpr int Nx = 4096, Ny = 4096, H = 1024, Dv = 1024, Kin = 1024;

    char* ws = (char*)d_ws;
    size_t off = 0;
    auto carve = [&](size_t bytes) {
        char* p = ws + off;
        off += (bytes + 255) & ~(size_t)255;
        return p;
    };

    unsigned short* q_bf  = (unsigned short*)carve((size_t)Nx * H * 2);   // 8 MB
    unsigned short* k_bf  = (unsigned short*)carve((size_t)Ny * H * 2);   // 8 MB
    unsigned short* vt_bf = (unsigned short*)carve((size_t)Dv * Ny * 2);  // 8 MB
    float*          lsum  = (float*)carve((size_t)Nx * sizeof(float));    // 16 KB

    unsigned short* P_bf  = (unsigned short*)carve((size_t)Nx * Ny * 2);  // 32 MB
    unsigned short* parts = (unsigned short*)(ws + off);                  // 4 x 8 MB
    const size_t need_parts = off + 4 * (size_t)Nx * Dv * 2;
    const bool useParts = ws_size >= need_parts;

    if (!useParts)
        hipMemsetAsync(d_out, 0, (size_t)Nx * Dv * sizeof(float), stream);

    // phase 1: projections directly from fp32 (cast fused into staging); zeroes lsum
    proj_batched_f32<<<768, 256, 0, stream>>>(x, y, Wq, Wk, Wv,
                                              q_bf, k_bf, vt_bf, bq, bk, bv, lsum);

    // phase 2a: P = exp(q k^T / 32), lsum row sums (1024 blocks)
    const float scale2 = 1.4426950408889634f / 32.0f;  // log2(e)/sqrt(H)
    scores_gemm<<<dim3(Ny / 128, Nx / 128), 256, 0, stream>>>(q_bf, k_bf, P_bf, lsum, scale2);

    // phase 2b: split-K x4, bf16 partials (1024 blocks, XCD-swizzled)
    if (useParts) {
        out_gemm_splitk<0><<<1024, 256, 0, stream>>>(P_bf, vt_bf, parts);
        reduce_norm<<<Nx * Dv / 4 / 256, 256, 0, stream>>>(parts, lsum, (float*)d_out);
    } else {
        out_gemm_splitk<1><<<1024, 256, 0, stream>>>(P_bf, vt_bf, d_out);
        norm_rows<<<Nx * Dv / 4 / 256, 256, 0, stream>>>((float*)d_out, lsum);
    }
}